// Round 12
// baseline (57.259 us; speedup 1.0000x reference)
//
#include <hip/hip_runtime.h>

typedef float f32x16 __attribute__((ext_vector_type(16)));
typedef short s16x8  __attribute__((ext_vector_type(8)));

#define B_SZ 4096
#define C_N  64
#define D_K  512
#define H_N  1024
#define BK   32                 // k per tile
#define NT   16                 // 512/32 tiles
#define ROWS 128                // rows per block pass (4 m-frags of 32)
#define HSLICE 256              // h per block; 4 slices per company
#define ZP_OFF_BYTES 32768
#define ZP_ROWS (B_SZ + 128)

__device__ __forceinline__ short f2bf(float f){
  unsigned u = __float_as_uint(f);
  u += 0x7FFFu + ((u >> 16) & 1u);   // RTNE
  return (short)(u >> 16);
}
// A&S 7.1.26, |err| <= 1.5e-7
__device__ __forceinline__ float erf_fast(float x){
  float ax = fabsf(x);
  float t = __builtin_amdgcn_rcpf(1.0f + 0.3275911f * ax);
  float p = t * (0.254829592f + t * (-0.284496736f + t * (1.421413741f +
            t * (-1.453152027f + t * 1.061405429f))));
  float r = 1.0f - p * __expf(-ax * ax);
  return copysignf(r, x);
}
__device__ __forceinline__ float gelu_exact(float x){
  return 0.5f * x * (1.0f + erf_fast(x * 0.70710678118654752f));
}

// count + scan only (single block of 1024)
__global__ void k_cs(const int* __restrict__ cid, int* __restrict__ offsets,
                     int* __restrict__ cursor){
  __shared__ int hist[C_N];
  const int tid = threadIdx.x;
  if (tid < C_N) hist[tid] = 0;
  __syncthreads();
  for (int i = tid; i < B_SZ; i += 1024) atomicAdd(&hist[cid[i]], 1);
  __syncthreads();
  if (tid < 64){
    int v = hist[tid];
    int x = v;
    #pragma unroll
    for (int d = 1; d < 64; d <<= 1){
      int y = __shfl_up(x, d, 64);
      if (tid >= d) x += y;
    }
    offsets[tid] = x - v;
    cursor[tid]  = x - v;
    if (tid == 63) offsets[64] = x;
  }
}

// scatter + bucket + out-init + bf16 row pack, fused. 64 blocks x 256.
__global__ void k_pack(const int* __restrict__ cid, const float* __restrict__ z,
                       const float* __restrict__ b2, int* __restrict__ cursor,
                       int* __restrict__ bucket, short* __restrict__ zp,
                       float* __restrict__ out){
  __shared__ int pos_s[64];
  const int tid = threadIdx.x;
  const int base = blockIdx.x * 64;
  if (tid < 64){
    int i = base + tid;
    int c = cid[i];
    int p = atomicAdd(&cursor[c], 1);
    pos_s[tid] = p;
    bucket[p] = i;
    out[i] = b2[c];
  }
  __syncthreads();
  #pragma unroll
  for (int j = 0; j < 16; ++j){
    int u = tid + 256 * j;            // 4096 units = 64 samples x 64 octets
    int s = u >> 6, oct = u & 63;
    const float* src = z + (size_t)(base + s) * D_K + oct * 8;
    float4 a = *(const float4*)src;
    float4 b = *(const float4*)(src + 4);
    s16x8 v;
    v[0]=f2bf(a.x); v[1]=f2bf(a.y); v[2]=f2bf(a.z); v[3]=f2bf(a.w);
    v[4]=f2bf(b.x); v[5]=f2bf(b.y); v[6]=f2bf(b.z); v[7]=f2bf(b.w);
    *(s16x8*)(zp + ((size_t)pos_s[s] << 9) + oct * 8) = v;
  }
}

__global__ __launch_bounds__(512, 1) void k_main(
    const short* __restrict__ zp, const float* __restrict__ W1,
    const float* __restrict__ b1, const float* __restrict__ W2,
    const int* __restrict__ offsets, const int* __restrict__ bucket,
    float* __restrict__ out)
{
  __shared__ float B_lds[3][BK * HSLICE];  // 96 KB: [k][h] f32
  __shared__ s16x8 A_lds[3][512];          // 24 KB: [ks*256+m*64+lane] bf16 frags
  __shared__ float partial[ROWS];          // 512 B -> 120.5 KB total: 1 block/CU

  // bid = hs*64 + c : bid%8 = c%8 -> a company's 4 blocks + its zp on one XCD;
  // the 4 hs panels jointly cover each full 4 KB W1 row.
  const int bid = blockIdx.x;
  const int c = bid & 63, hs = bid >> 6;   // hs 0..3
  const int off_c = offsets[c];
  const int n_c = offsets[c + 1] - off_c;
  if (n_c == 0) return;

  const int tid  = threadIdx.x;
  const int lane = tid & 63, wave = tid >> 6;    // 8 waves x 32 h
  const int l31 = lane & 31, lhi = lane >> 5;
  const int hcol = hs * HSLICE + wave * 32 + l31;
  const float b1v = b1[c * H_N + hcol];
  const float w2v = W2[c * H_N + hcol];
  const float* Wpanel = W1 + (size_t)c * D_K * H_N + hs * HSLICE;

  // A staging decomposition: tid = ks*256 + m*64 + lane (dest linear in tid)
  const int arow  = ((tid >> 6) & 3) * 32 + (tid & 31);           // m*32 + l31
  const int akoff = ((tid >> 8) << 4) | (((tid >> 5) & 1) << 3);  // ks*16+lhi*8

  if (tid < ROWS) partial[tid] = 0.0f;

  for (int rb = 0; rb < n_c; rb += ROWS){
    const short* zrow = zp + ((size_t)(off_c + rb + arow) << 9) + akoff;

    // 5 uniform gload_lds per tile: 4xB (each wave-instr = 1 KB contiguous) + 1xA
    auto stage = [&](int t){
      const int sl = t % 3;
      #pragma unroll
      for (int s = 0; s < 4; ++s){
        __builtin_amdgcn_global_load_lds(
          (const __attribute__((address_space(1))) void*)
            (Wpanel + (size_t)(t * BK + wave + s * 8) * H_N + (tid & 63) * 4),
          (__attribute__((address_space(3))) void*)
            (&B_lds[sl][tid * 4 + s * 2048]), 16, 0, 0);
      }
      __builtin_amdgcn_global_load_lds(
        (const __attribute__((address_space(1))) void*)(zrow + t * BK),
        (__attribute__((address_space(3))) void*)(&A_lds[sl][tid]), 16, 0, 0);
    };

    stage(0); stage(1);                    // 10 loads in flight

    f32x16 acc[4];
    acc[0] = 0; acc[1] = 0; acc[2] = 0; acc[3] = 0;

    for (int t = 0; t < NT; ++t){
      if (t + 2 < NT) stage(t + 2);        // slot (t+2)%3 == (t-1)%3, consumed
      if      (t <  NT - 2) asm volatile("s_waitcnt vmcnt(10)" ::: "memory");
      else if (t == NT - 2) asm volatile("s_waitcnt vmcnt(5)"  ::: "memory");
      else                  asm volatile("s_waitcnt vmcnt(0)"  ::: "memory");
      __builtin_amdgcn_s_barrier();        // tile t fully in LDS

      const int sl = t % 3;
      const float* Bt = &B_lds[sl][0];
      const s16x8* At = &A_lds[sl][0];
      #pragma unroll
      for (int ks = 0; ks < 2; ++ks){
        s16x8 bf;
        #pragma unroll
        for (int e = 0; e < 8; ++e)
          bf[e] = f2bf(Bt[(ks * 16 + lhi * 8 + e) * HSLICE + wave * 32 + l31]);
        #pragma unroll
        for (int m = 0; m < 4; ++m){
          s16x8 af = At[ks * 256 + m * 64 + lane];   // lane*16 B: conflict-free
          acc[m] = __builtin_amdgcn_mfma_f32_32x32x16_bf16(af, bf, acc[m], 0, 0, 0);
        }
      }
      __builtin_amdgcn_s_barrier();        // all waves done with slot sl
    }

    // ---- epilogue: GELU + W2 dot, 32-lane reduce, LDS partial, flush ----
    #pragma unroll
    for (int m = 0; m < 4; ++m){
      #pragma unroll
      for (int r = 0; r < 16; ++r){
        int r_loc = m * 32 + (r & 3) + 8 * (r >> 2) + 4 * lhi;
        float v = gelu_exact(acc[m][r] + b1v) * w2v;
        v += __shfl_xor(v, 1, 64);
        v += __shfl_xor(v, 2, 64);
        v += __shfl_xor(v, 4, 64);
        v += __shfl_xor(v, 8, 64);
        v += __shfl_xor(v, 16, 64);
        if (l31 == 0 && rb + r_loc < n_c)
          atomicAdd(&partial[r_loc], v);
      }
    }
    __syncthreads();
    if (tid < ROWS){
      int g = rb + tid;
      if (g < n_c)
        atomicAdd(&out[bucket[off_c + g]], partial[tid]);
      partial[tid] = 0.0f;
    }
    __syncthreads();
  }
}

extern "C" void kernel_launch(void* const* d_in, const int* in_sizes, int n_in,
                              void* d_out, int out_size, void* d_ws, size_t ws_size,
                              hipStream_t stream){
  const float* z  = (const float*)d_in[0];
  const int*   cid= (const int*)  d_in[1];
  const float* W1 = (const float*)d_in[2];
  const float* b1 = (const float*)d_in[3];
  const float* W2 = (const float*)d_in[4];
  const float* b2 = (const float*)d_in[5];
  float* out = (float*)d_out;

  int*   ws      = (int*)d_ws;
  int*   offsets = ws;                                   // [65]
  int*   cursor  = ws + 96;                              // [64]
  int*   bucket  = ws + 192;                             // [4096]
  short* zp      = (short*)((char*)d_ws + ZP_OFF_BYTES); // [ZP_ROWS*512] bf16

  k_cs   <<<1, 1024, 0, stream>>>(cid, offsets, cursor);
  k_pack <<<64, 256, 0, stream>>>(cid, z, b2, cursor, bucket, zp, out);
  k_main <<<C_N * 4, 512, 0, stream>>>(zp, W1, b1, W2, offsets, bucket, out);
}

// Round 13
// 53.353 us; speedup vs baseline: 1.0732x; 1.0732x over previous
//
#include <hip/hip_runtime.h>

typedef float f32x16 __attribute__((ext_vector_type(16)));
typedef short s16x8  __attribute__((ext_vector_type(8)));

#define B_SZ 4096
#define C_N  64
#define D_K  512
#define H_N  1024
#define BK   16                 // k per tile
#define NT   32                 // 512/16 tiles
#define ROWS 128                // rows per block pass (4 m-frags of 32)
#define NSLOT 6                 // pipeline slots (issue-to-use depth 5)
#define ZP_OFF_BYTES 32768
#define ZP_ROWS (B_SZ + 128)

__device__ __forceinline__ short f2bf(float f){
  unsigned u = __float_as_uint(f);
  u += 0x7FFFu + ((u >> 16) & 1u);   // RTNE
  return (short)(u >> 16);
}
// A&S 7.1.26, |err| <= 1.5e-7
__device__ __forceinline__ float erf_fast(float x){
  float ax = fabsf(x);
  float t = __builtin_amdgcn_rcpf(1.0f + 0.3275911f * ax);
  float p = t * (0.254829592f + t * (-0.284496736f + t * (1.421413741f +
            t * (-1.453152027f + t * 1.061405429f))));
  float r = 1.0f - p * __expf(-ax * ax);
  return copysignf(r, x);
}
__device__ __forceinline__ float gelu_exact(float x){
  return 0.5f * x * (1.0f + erf_fast(x * 0.70710678118654752f));
}

// Fused count + scan + scatter + out-init. One block of 1024.  (R8 verbatim)
__global__ void k_prep(const int* __restrict__ cid, const float* __restrict__ b2,
                       int* __restrict__ offsets, int* __restrict__ bucket,
                       float* __restrict__ out){
  __shared__ int hist[C_N];
  const int tid = threadIdx.x;
  if (tid < C_N) hist[tid] = 0;
  __syncthreads();
  for (int i = tid; i < B_SZ; i += 1024) atomicAdd(&hist[cid[i]], 1);
  __syncthreads();
  if (tid < 64){
    int v = hist[tid];
    int x = v;
    #pragma unroll
    for (int d = 1; d < 64; d <<= 1){
      int y = __shfl_up(x, d, 64);
      if (tid >= d) x += y;
    }
    offsets[tid] = x - v;
    if (tid == 63) offsets[64] = x;
    hist[tid] = x - v;                  // reuse as cursor
  }
  __syncthreads();
  for (int i = tid; i < B_SZ; i += 1024){
    int c = cid[i];
    int p = atomicAdd(&hist[c], 1);
    bucket[p] = i;
    out[i] = b2[c];
  }
}

// Pack z into bucket-ordered bf16 rows. (R8 verbatim)
__global__ void k_zpack(const float* __restrict__ z, const int* __restrict__ bucket,
                        short* __restrict__ zp){
  int u = blockIdx.x * 256 + threadIdx.x;     // 262144 units of 8 elems
  int slot = u >> 6;
  int k0 = (u & 63) * 8;
  const float* src = z + (size_t)bucket[slot] * D_K + k0;
  float4 a = *(const float4*)src;
  float4 b = *(const float4*)(src + 4);
  s16x8 v;
  v[0]=f2bf(a.x); v[1]=f2bf(a.y); v[2]=f2bf(a.z); v[3]=f2bf(a.w);
  v[4]=f2bf(b.x); v[5]=f2bf(b.y); v[6]=f2bf(b.z); v[7]=f2bf(b.w);
  *(s16x8*)(zp + ((size_t)slot << 9) + k0) = v;
}

__global__ __launch_bounds__(256, 2) void k_main(
    const short* __restrict__ zp, const float* __restrict__ W1,
    const float* __restrict__ b1, const float* __restrict__ W2,
    const int* __restrict__ offsets, const int* __restrict__ bucket,
    float* __restrict__ out)
{
  // 6-slot pipelined LDS: B slots [16k][128h] f32, A slots [128row][16k] bf16
  __shared__ float B_lds[NSLOT][BK * 128];   // 48 KB
  __shared__ char  A_lds[NSLOT][4096];       // 24 KB
  __shared__ float partial[ROWS];            // 512 B (72.7 KB -> 2 blocks/CU)

  // bid = hs*64 + c : bid%8 = c%8 -> one company per XCD (zp L2 locality);
  // the 8 hs-blocks of a company read DISJOINT W1 panels: W1 fetched once.
  const int bid = blockIdx.x;
  const int c = bid & 63, hs = bid >> 6;
  const int off_c = offsets[c];
  const int n_c = offsets[c + 1] - off_c;
  if (n_c == 0) return;

  const int tid  = threadIdx.x;
  const int lane = tid & 63, wave = tid >> 6;    // 4 waves x 32 h
  const int l31 = lane & 31, lhi = lane >> 5;
  const int hcol = hs * 128 + wave * 32 + l31;
  const float b1v = b1[c * H_N + hcol];
  const float w2v = W2[c * H_N + hcol];
  const float* Wpanel = W1 + (size_t)c * D_K * H_N + hs * 128;

  // staging geometry (all thread-uniform: exactly 3 gload_lds per tile)
  const int r0 = tid >> 5;                 // B k-row 0..7
  const int hc = (tid & 31) * 4;           // B h-col (f32)
  const int arow = tid >> 1;               // A row 0..127
  const int akh  = (tid & 1) * 8;          // A k-half (bf16 elems)

  if (tid < ROWS) partial[tid] = 0.0f;

  for (int rb = 0; rb < n_c; rb += ROWS){
    const short* zrow = zp + ((size_t)(off_c + rb + arow) << 9) + akh;

    auto stage = [&](int t){
      const int s = t % NSLOT;
      const float* bsrc = Wpanel + (size_t)(t * BK + r0) * H_N + hc;
      // B: dst byte offset r0*512 + hc*4 == tid*16 (linear, wave-uniform+lane*16)
      __builtin_amdgcn_global_load_lds(
        (const __attribute__((address_space(1))) void*)bsrc,
        (__attribute__((address_space(3))) void*)(&B_lds[s][r0 * 128 + hc]), 16, 0, 0);
      __builtin_amdgcn_global_load_lds(
        (const __attribute__((address_space(1))) void*)(bsrc + 8 * H_N),
        (__attribute__((address_space(3))) void*)(&B_lds[s][(r0 + 8) * 128 + hc]), 16, 0, 0);
      // A: dst byte offset arow*32 + akh*2 == tid*16 (linear)
      __builtin_amdgcn_global_load_lds(
        (const __attribute__((address_space(1))) void*)(zrow + t * BK),
        (__attribute__((address_space(3))) void*)(&A_lds[s][tid * 16]), 16, 0, 0);
    };

    stage(0); stage(1); stage(2); stage(3); stage(4);   // 15 loads in flight

    f32x16 acc[4];
    acc[0] = 0; acc[1] = 0; acc[2] = 0; acc[3] = 0;

    for (int t = 0; t < NT; ++t){
      if (t + 5 < NT) stage(t + 5);        // slot (t+5)%6 == (t-1)%6, consumed
      // retire tile t's 3 loads; keep up to 5 newer stages (15) outstanding
      if      (t <  NT - 5) asm volatile("s_waitcnt vmcnt(15)" ::: "memory");
      else if (t == NT - 5) asm volatile("s_waitcnt vmcnt(12)" ::: "memory");
      else if (t == NT - 4) asm volatile("s_waitcnt vmcnt(9)"  ::: "memory");
      else if (t == NT - 3) asm volatile("s_waitcnt vmcnt(6)"  ::: "memory");
      else if (t == NT - 2) asm volatile("s_waitcnt vmcnt(3)"  ::: "memory");
      else                  asm volatile("s_waitcnt vmcnt(0)"  ::: "memory");
      __builtin_amdgcn_s_barrier();        // tile t fully in LDS for all waves

      const int s = t % NSLOT;
      const float* Bt = &B_lds[s][0];
      s16x8 bf;
      #pragma unroll
      for (int e = 0; e < 8; ++e)
        bf[e] = f2bf(Bt[(lhi * 8 + e) * 128 + wave * 32 + l31]);
      const s16x8* At = (const s16x8*)&A_lds[s][0];
      #pragma unroll
      for (int m = 0; m < 4; ++m){
        s16x8 af = At[(m * 32 + l31) * 2 + lhi];
        acc[m] = __builtin_amdgcn_mfma_f32_32x32x16_bf16(af, bf, acc[m], 0, 0, 0);
      }
      __builtin_amdgcn_s_barrier();        // all waves done with slot s
    }

    // ---- epilogue: GELU + W2 dot, 32-lane reduce, LDS partial, flush ----
    #pragma unroll
    for (int m = 0; m < 4; ++m){
      #pragma unroll
      for (int r = 0; r < 16; ++r){
        int r_loc = m * 32 + (r & 3) + 8 * (r >> 2) + 4 * lhi;
        float v = gelu_exact(acc[m][r] + b1v) * w2v;
        v += __shfl_xor(v, 1, 64);
        v += __shfl_xor(v, 2, 64);
        v += __shfl_xor(v, 4, 64);
        v += __shfl_xor(v, 8, 64);
        v += __shfl_xor(v, 16, 64);
        if (l31 == 0 && rb + r_loc < n_c)
          atomicAdd(&partial[r_loc], v);
      }
    }
    __syncthreads();
    if (tid < ROWS){
      int g = rb + tid;
      if (g < n_c)
        atomicAdd(&out[bucket[off_c + g]], partial[tid]);
      partial[tid] = 0.0f;                 // re-init for next pass (rare)
    }
    __syncthreads();
  }
}

extern "C" void kernel_launch(void* const* d_in, const int* in_sizes, int n_in,
                              void* d_out, int out_size, void* d_ws, size_t ws_size,
                              hipStream_t stream){
  const float* z  = (const float*)d_in[0];
  const int*   cid= (const int*)  d_in[1];
  const float* W1 = (const float*)d_in[2];
  const float* b1 = (const float*)d_in[3];
  const float* W2 = (const float*)d_in[4];
  const float* b2 = (const float*)d_in[5];
  float* out = (float*)d_out;

  int*   ws      = (int*)d_ws;
  int*   offsets = ws;                                   // [65]
  int*   bucket  = ws + 128;                             // [4096]
  short* zp      = (short*)((char*)d_ws + ZP_OFF_BYTES); // [ZP_ROWS*512] bf16

  k_prep <<<1, 1024, 0, stream>>>(cid, b2, offsets, bucket, out);
  k_zpack<<<1024, 256, 0, stream>>>(z, bucket, zp);
  k_main <<<C_N * 8, 256, 0, stream>>>(zp, W1, b1, W2, offsets, bucket, out);
}